// Round 7
// baseline (203.816 us; speedup 1.0000x reference)
//
#include <hip/hip_runtime.h>
#include <hip/hip_bf16.h>

typedef unsigned short u16;
typedef unsigned int u32;
typedef __bf16 v8bf __attribute__((ext_vector_type(8)));
typedef float f32x4 __attribute__((ext_vector_type(4)));
typedef unsigned int u32x4 __attribute__((ext_vector_type(4)));

constexpr int BATCH = 2048;
constexpr int DIM   = 512;
constexpr int NCLS  = 10000;
constexpr int NPAD  = 10240;   // 80 * 128 (zero-padded rows)

#define F_S     30.0f
#define F_COS_M 0.9800665778412416f
#define F_SIN_M 0.19866933079506122f
#define F_TH   (-0.9800665778412416f)
#define F_MM    0.03973386615901224f

#define G_AAM  640    // 8 bm (256-row tiles) x 80 bn (128-col tiles)
#define G_CC   256    // 8 bm x 32 bn (64-col tiles)

static __device__ __forceinline__ float clampf(float v, float lo, float hi) {
    return fminf(fmaxf(v, lo), hi);
}
static __device__ __forceinline__ u16 f2bf(float v) {
    __hip_bfloat16 h = __float2bfloat16(v);
    return __builtin_bit_cast(unsigned short, h);
}
// async global->LDS, 16B per lane. LDS dest is wave-uniform base + lane*16.
static __device__ __forceinline__ void glds16(const void* g, void* l) {
    __builtin_amdgcn_global_load_lds(
        (const __attribute__((address_space(1))) unsigned int*)g,
        (__attribute__((address_space(3))) unsigned int*)l, 16, 0, 0);
}
static __device__ __forceinline__ float blk_sum(float v, float* sh, int t) {
#pragma unroll
    for (int o = 32; o > 0; o >>= 1) v += __shfl_down(v, o, 64);
    __syncthreads();
    if ((t & 63) == 0) sh[t >> 6] = v;
    __syncthreads();
    return sh[0] + sh[1] + sh[2] + sh[3];
}

// ============ normalize: one WAVE per row, no barriers ============
__global__ __launch_bounds__(256) void norm_all_kernel(const float* __restrict__ x,
                                                       const float* __restrict__ w,
                                                       const float* __restrict__ wm,
                                                       const float* __restrict__ wn,
                                                       const int* __restrict__ label,
                                                       u32* __restrict__ xnb,
                                                       u32* __restrict__ wb,
                                                       u32* __restrict__ wqb,
                                                       u32* __restrict__ wkb,
                                                       float* __restrict__ zacc) {
    const int t = threadIdx.x, lane = t & 63, wv = t >> 6;
    const int b = blockIdx.x;
    if (b < 33) zacc[b * 256 + t] = 0.f;   // zero accumulators (8448 >= 8196 used)

    const int row = b * 4 + wv;
    const float* src;
    u32* dst;
    if (row < BATCH) {
        src = x + (size_t)row * DIM;
        dst = xnb + (size_t)row * 256;
    } else if (row < BATCH + NPAD) {
        const int r = row - BATCH;
        dst = wb + (size_t)r * 256;
        if (r >= NCLS) {   // zero pad rows (wave-uniform)
            u32x4 z = {0, 0, 0, 0};
            ((u32x4*)dst)[lane] = z;
            return;
        }
        src = w + (size_t)r * DIM;
    } else if (row < BATCH + NPAD + BATCH) {
        const int i = row - (BATCH + NPAD);
        src = wm + (size_t)label[i] * DIM;
        dst = wqb + (size_t)i * 256;
    } else {
        const int i = row - (BATCH + NPAD + BATCH);
        src = wn + (size_t)label[i] * DIM;
        dst = wkb + (size_t)i * 256;
    }
    const float4 v0 = ((const float4*)src)[lane * 2];
    const float4 v1 = ((const float4*)src)[lane * 2 + 1];
    float s = v0.x * v0.x + v0.y * v0.y + v0.z * v0.z + v0.w * v0.w
            + v1.x * v1.x + v1.y * v1.y + v1.z * v1.z + v1.w * v1.w;
#pragma unroll
    for (int o = 32; o > 0; o >>= 1) s += __shfl_xor(s, o, 64);
    const float inv = 1.0f / fmaxf(sqrtf(s), 1e-12f);
    u32x4 o4;
    o4[0] = (u32)f2bf(v0.x * inv) | ((u32)f2bf(v0.y * inv) << 16);
    o4[1] = (u32)f2bf(v0.z * inv) | ((u32)f2bf(v0.w * inv) << 16);
    o4[2] = (u32)f2bf(v1.x * inv) | ((u32)f2bf(v1.y * inv) << 16);
    o4[3] = (u32)f2bf(v1.z * inv) | ((u32)f2bf(v1.w * inv) << 16);
    ((u32x4*)dst)[lane] = o4;
}

// ============ FUSED GEMM, 512 threads: [0,640)=AAM 256x128, [640,896)=CC 256x64 ============
// glds staging + XOR swizzle (0-conflict, proven r5). 256-row M-tile doubles MFMA per block,
// amortizing per-block fixed cost F (prologue latency + epilogue) over 2x compute.
__global__ __launch_bounds__(512) void gemm_fused_kernel(const u16* __restrict__ A,
                                                         const u16* __restrict__ Bw,
                                                         const u16* __restrict__ Bq,
                                                         const u16* __restrict__ Bk,
                                                         const int* __restrict__ label,
                                                         float* __restrict__ sumexp,
                                                         float* __restrict__ sumlogit,
                                                         float* __restrict__ philab,
                                                         float* __restrict__ sim,
                                                         float* __restrict__ msum,
                                                         float* __restrict__ mcnt,
                                                         float* __restrict__ ap) {
    __shared__ __align__(16) u16 sA[256 * 64];   // 32 KB, unpadded (glds)
    __shared__ __align__(16) u16 sB[128 * 64];   // 16 KB (CC: Qs=[0,4096), Ks=[4096,8192))
    __shared__ float red0[256];
    __shared__ float red1[256];

    const int t = threadIdx.x;                  // 0..511, 8 waves
    const int lane = t & 63, wave = t >> 6;
    const int fr = lane & 15, quad = lane >> 4;
    const int swz = fr & 7;

    if (t < 256) { red0[t] = 0.f; red1[t] = 0.f; }

    const int srow = t >> 3;                    // 0..63
    const int scg  = (t & 7) ^ (srow & 7);      // swizzled global chunk (shots of 64 rows keep row%8)

    if (blockIdx.x < G_AAM) {
        // ---------------- AAM role: 256x128 tile, BK=64 ----------------
        const int flat = blockIdx.x;
        const int xcd = flat & 7, r = flat >> 3;   // r 0..79
        const int bm = r & 7;
        const int bn = (r >> 3) * 8 + xcd;         // 10 bn per xcd: 1.28 MB B + 2 MB A per XCD L2

        const int wm = (wave >> 1) * 64;           // 0,64,128,192
        const int wn = (wave & 1) * 64;            // 0,64
        const u16* ag = A  + (size_t)(bm * 256 + srow) * DIM + scg * 8;
        const u16* bg = Bw + (size_t)(bn * 128 + srow) * DIM + scg * 8;
        u16* al = &sA[t * 8];
        u16* bl = &sB[t * 8];

        f32x4 acc[4][4] = {};

        for (int k0 = 0; k0 < DIM; k0 += 64) {
#pragma unroll
            for (int r2 = 0; r2 < 4; r2++)
                glds16(ag + (size_t)(r2 * 64) * DIM + k0, al + r2 * 4096);
#pragma unroll
            for (int r2 = 0; r2 < 2; r2++)
                glds16(bg + (size_t)(r2 * 64) * DIM + k0, bl + r2 * 4096);
            __syncthreads();
#pragma unroll
            for (int ks = 0; ks < 2; ks++) {
                const int slot = ((ks << 2) | quad) ^ swz;
                v8bf af[4], bf[4];
#pragma unroll
                for (int f = 0; f < 4; f++) {
                    af[f] = __builtin_bit_cast(v8bf, *(const u32x4*)&sA[(wm + f * 16 + fr) * 64 + slot * 8]);
                    bf[f] = __builtin_bit_cast(v8bf, *(const u32x4*)&sB[(wn + f * 16 + fr) * 64 + slot * 8]);
                }
#pragma unroll
                for (int i = 0; i < 4; i++)
#pragma unroll
                    for (int j = 0; j < 4; j++)
                        acc[i][j] = __builtin_amdgcn_mfma_f32_16x16x32_bf16(af[i], bf[j], acc[i][j], 0, 0, 0);
            }
            __syncthreads();
        }

        // Epilogue: per-row partial Σexp(logit), Σlogit (logits<=30 -> fp32 safe, no max-sub)
#pragma unroll
        for (int i = 0; i < 4; i++) {
#pragma unroll
            for (int r3 = 0; r3 < 4; r3++) {
                const int ml = wm + i * 16 + quad * 4 + r3;     // 0..255
                const int mg = bm * 256 + ml;
                const int lab = label[mg];
                float esum = 0.f, lsum = 0.f;
#pragma unroll
                for (int j = 0; j < 4; j++) {
                    const int ng = bn * 128 + wn + j * 16 + fr;
                    if (ng < NCLS) {
                        float c = acc[i][j][r3];
                        float logit;
                        if (ng == lab) {
                            float sine = sqrtf(clampf(1.f - c * c, 0.f, 1.f));
                            float phi = c * F_COS_M - sine * F_SIN_M;
                            float val = ((c - F_TH) > 0.f) ? phi : (c - F_MM);
                            logit = F_S * val;
                            philab[mg] = logit;
                        } else {
                            logit = F_S * c;
                        }
                        esum += __expf(logit);
                        lsum += logit;
                    }
                }
#pragma unroll
                for (int off = 1; off < 16; off <<= 1) {
                    esum += __shfl_xor(esum, off, 64);
                    lsum += __shfl_xor(lsum, off, 64);
                }
                if (fr == 0) {
                    atomicAdd(&red0[ml], esum);
                    atomicAdd(&red1[ml], lsum);
                }
            }
        }
        __syncthreads();
        if (t < 256) {
            atomicAdd(&sumexp[bm * 256 + t], red0[t]);
            atomicAdd(&sumlogit[bm * 256 + t], red1[t]);
        }
    } else {
        // ---------------- CC role: dual GEMM, 256x64 tile, BK=64 ----------------
        const int c = blockIdx.x - G_AAM;          // 0..255
        const int xcd = c & 7, r = c >> 3;         // r 0..31
        const int bm = r & 7;
        const int bn = (r >> 3) * 8 + xcd;         // 0..31

        const int wm = (wave >> 1) * 64;           // 0..192
        const int wn = (wave & 1) * 32;            // 0,32
        u16* Qs = sB;
        u16* Ks = sB + 64 * 64;

        const u16* ag = A  + (size_t)(bm * 256 + srow) * DIM + scg * 8;
        const u16* qg = Bq + (size_t)(bn * 64 + srow) * DIM + scg * 8;
        const u16* kg = Bk + (size_t)(bn * 64 + srow) * DIM + scg * 8;
        u16* al = &sA[t * 8];
        u16* ql = &Qs[t * 8];   // 64-row tile: one 512-thread shot
        u16* kl = &Ks[t * 8];

        f32x4 aq[4][2] = {};
        f32x4 ak[4][2] = {};

        for (int k0 = 0; k0 < DIM; k0 += 64) {
#pragma unroll
            for (int r2 = 0; r2 < 4; r2++)
                glds16(ag + (size_t)(r2 * 64) * DIM + k0, al + r2 * 4096);
            glds16(qg + k0, ql);
            glds16(kg + k0, kl);
            __syncthreads();
#pragma unroll
            for (int ks = 0; ks < 2; ks++) {
                const int slot = ((ks << 2) | quad) ^ swz;
                v8bf af[4], qf[2], kf[2];
#pragma unroll
                for (int f = 0; f < 4; f++)
                    af[f] = __builtin_bit_cast(v8bf, *(const u32x4*)&sA[(wm + f * 16 + fr) * 64 + slot * 8]);
#pragma unroll
                for (int f = 0; f < 2; f++) {
                    qf[f] = __builtin_bit_cast(v8bf, *(const u32x4*)&Qs[(wn + f * 16 + fr) * 64 + slot * 8]);
                    kf[f] = __builtin_bit_cast(v8bf, *(const u32x4*)&Ks[(wn + f * 16 + fr) * 64 + slot * 8]);
                }
#pragma unroll
                for (int i = 0; i < 4; i++)
#pragma unroll
                    for (int j = 0; j < 2; j++) {
                        aq[i][j] = __builtin_amdgcn_mfma_f32_16x16x32_bf16(af[i], qf[j], aq[i][j], 0, 0, 0);
                        ak[i][j] = __builtin_amdgcn_mfma_f32_16x16x32_bf16(af[i], kf[j], ak[i][j], 0, 0, 0);
                    }
            }
            __syncthreads();
        }

        int lab_n[2];
#pragma unroll
        for (int j = 0; j < 2; j++) lab_n[j] = label[bn * 64 + wn + j * 16 + fr];

#pragma unroll
        for (int i = 0; i < 4; i++) {
#pragma unroll
            for (int r3 = 0; r3 < 4; r3++) {
                const int ml = wm + i * 16 + quad * 4 + r3;     // 0..255
                const int mg = bm * 256 + ml;
                const int lm = label[mg];
                float ms = 0.f, mc = 0.f;
#pragma unroll
                for (int j = 0; j < 2; j++) {
                    const int ng = bn * 64 + wn + j * 16 + fr;
                    float s = aq[i][j][r3] * ak[i][j][r3];
                    sim[(size_t)mg * BATCH + ng] = s;
                    if (lab_n[j] == lm) { ms += s; mc += 1.f; }
                    if (mg == ng) ap[mg] = s;   // unique writer; read next dispatch
                }
#pragma unroll
                for (int off = 1; off < 16; off <<= 1) {
                    ms += __shfl_xor(ms, off, 64);
                    mc += __shfl_xor(mc, off, 64);
                }
                if (fr == 0) {
                    atomicAdd(&red0[ml], ms);
                    atomicAdd(&red1[ml], mc);
                }
            }
        }
        __syncthreads();
        if (t < 256) {
            atomicAdd(&msum[bm * 256 + t], red0[t]);
            atomicAdd(&mcnt[bm * 256 + t], red1[t]);
        }
    }
}

// ============ CC pass 2 + finalize (atomics-only ticket, no fences) ============
// 512 blocks x 4 rows. All cross-block values flow through device-scope atomicAdds;
// ticket (acq_rel) elects the last block to compute the final scalar loss.
__global__ __launch_bounds__(256) void cc_pass2_kernel(const float* __restrict__ sim,
                                                       const int* __restrict__ label,
                                                       const float* __restrict__ msum,
                                                       const float* __restrict__ mcnt,
                                                       const float* __restrict__ ap,
                                                       const float* __restrict__ sumexp,
                                                       const float* __restrict__ sumlogit,
                                                       const float* __restrict__ philab,
                                                       float* __restrict__ zn,
                                                       float* __restrict__ zneg,
                                                       float* __restrict__ accA,
                                                       unsigned* __restrict__ tick,
                                                       float* __restrict__ out) {
    __shared__ __align__(16) float cam_s[BATCH];
    __shared__ __align__(16) float sam_s[BATCH];
    __shared__ float sh[4];
    const int t = threadIdx.x, b = blockIdx.x;

    for (int j = t; j < BATCH; j += 256) {
        float cam = clampf(msum[j] / mcnt[j], 0.f, 1.f);   // mcnt >= 1 (diagonal)
        cam_s[j] = cam;
        sam_s[j] = sqrtf(clampf(1.f - cam, 0.f, 1.f));
    }
    __syncthreads();

    float acc = 0.f;
#pragma unroll
    for (int row = 0; row < 4; row++) {
        const int i = b * 4 + row;
        const int li = label[i];
        const f32x4* simr = (const f32x4*)(sim + (size_t)i * BATCH);
        const f32x4* cap4 = (const f32x4*)cam_s;
        const f32x4* sap4 = (const f32x4*)sam_s;
#pragma unroll
        for (int k = 0; k < 2; k++) {
            const int jj = t + k * 256;
            f32x4 s4 = simr[jj];
            int4 l4i = ((const int4*)label)[jj];
            const int* l4 = (const int*)&l4i;
            f32x4 ca4 = cap4[jj];
            f32x4 sa4 = sap4[jj];
#pragma unroll
            for (int e = 0; e < 4; e++) {
                if (l4[e] != li) {
                    float can = clampf(s4[e], 0.f, 1.f);
                    float san = sqrtf(clampf(1.f - can, 0.f, 1.f));
                    float pns = san * ca4[e] + can * sa4[e];   // column-j broadcast
                    float pnc = sqrtf(clampf(1.f - pns, 0.f, 1.f));
                    acc += __expf(pns * F_COS_M - pnc * F_SIN_M);
                }
            }
        }
    }
    acc = blk_sum(acc, sh, t);

    if (t == 0) {
        // per-block partitions of the two small reductions (4 rows each)
        float apart = 0.f, epart = 0.f;
#pragma unroll
        for (int row = 0; row < 4; row++) {
            const int rr = b * 4 + row;
            float lse = logf(sumexp[rr]);
            apart += 0.9f * (philab[rr] - lse) + 1e-5f * (sumlogit[rr] - (float)NCLS * lse);
            float cam = cam_s[rr], sam = sam_s[rr];
            float cap = clampf(ap[rr], 0.f, 1.f);
            float sap = sqrtf(clampf(1.f - cap, 0.f, 1.f));
            float ppc = cap * cam - sap * sam;
            float pps = sqrtf(clampf(1.f - ppc, 0.f, 1.f));
            epart += __expf(1.f - (ppc * F_COS_M - pps * F_SIN_M));
        }
        atomicAdd(zn, acc);
        atomicAdd(accA, apart);
        atomicAdd(zneg, epart);
        unsigned old = __hip_atomic_fetch_add(tick, 1u, __ATOMIC_ACQ_REL, __HIP_MEMORY_SCOPE_AGENT);
        if (old == 511u) {   // last block: all 512 released their adds
            float znv = __hip_atomic_load(zn,   __ATOMIC_RELAXED, __HIP_MEMORY_SCOPE_AGENT);
            float aav = __hip_atomic_load(accA, __ATOMIC_RELAXED, __HIP_MEMORY_SCOPE_AGENT);
            float zgv = __hip_atomic_load(zneg, __ATOMIC_RELAXED, __HIP_MEMORY_SCOPE_AGENT);
            float aam = -aav / (float)BATCH;
            float z = logf(znv) + logf(zgv);
            float cc = (z > 0.f) ? (z + log1pf(__expf(-z))) : log1pf(__expf(z));
            out[0] = aam + cc;
        }
    }
}

extern "C" void kernel_launch(void* const* d_in, const int* in_sizes, int n_in,
                              void* d_out, int out_size, void* d_ws, size_t ws_size,
                              hipStream_t stream) {
    const float* x        = (const float*)d_in[0];
    const int*   label    = (const int*)d_in[1];
    const float* weight   = (const float*)d_in[2];
    const float* weight_m = (const float*)d_in[3];
    const float* weight_n = (const float*)d_in[4];
    float* out = (float*)d_out;
    char* ws = (char*)d_ws;

    const size_t o_xnb  = 0;
    const size_t o_wb   = o_xnb + (size_t)BATCH * DIM * 2;
    const size_t o_wqb  = o_wb  + (size_t)NPAD * DIM * 2;
    const size_t o_wkb  = o_wqb + (size_t)BATCH * DIM * 2;
    const size_t o_sim  = o_wkb + (size_t)BATCH * DIM * 2;
    const size_t o_misc = o_sim + (size_t)BATCH * BATCH * 4;

    u16* xnb = (u16*)(ws + o_xnb);
    u16* wb  = (u16*)(ws + o_wb);
    u16* wqb = (u16*)(ws + o_wqb);
    u16* wkb = (u16*)(ws + o_wkb);
    float* sim = (float*)(ws + o_sim);
    float* mf  = (float*)(ws + o_misc);

    // zeroed by norm_all (33*256 = 8448 floats)
    float* sumexp   = mf;               // 2048
    float* sumlogit = mf + 2048;        // 2048
    float* msum     = mf + 4096;        // 2048
    float* mcnt     = mf + 6144;        // 2048
    float* zn       = mf + 8192;        // 1
    float* zneg     = mf + 8193;        // 1
    float* accA     = mf + 8194;        // 1
    unsigned* tick  = (unsigned*)(mf + 8195);
    // non-zeroed (fully overwritten every launch)
    float* philab  = mf + 8448;         // 2048
    float* ap      = mf + 10496;        // 2048

    norm_all_kernel<<<(BATCH + NPAD + 2 * BATCH) / 4, 256, 0, stream>>>(
        x, weight, weight_m, weight_n, label,
        (u32*)xnb, (u32*)wb, (u32*)wqb, (u32*)wkb, mf);

    gemm_fused_kernel<<<G_AAM + G_CC, 512, 0, stream>>>(
        xnb, wb, wqb, wkb, label,
        sumexp, sumlogit, philab, sim, msum, mcnt, ap);

    cc_pass2_kernel<<<512, 256, 0, stream>>>(
        sim, label, msum, mcnt, ap,
        sumexp, sumlogit, philab, zn, zneg, accA, tick, out);
}

// Round 8
// 188.700 us; speedup vs baseline: 1.0801x; 1.0801x over previous
//
#include <hip/hip_runtime.h>
#include <hip/hip_bf16.h>

typedef unsigned short u16;
typedef unsigned char u8;
typedef unsigned int u32;
typedef float f32x4 __attribute__((ext_vector_type(4)));
typedef unsigned int u32x4 __attribute__((ext_vector_type(4)));
typedef unsigned int u32x2 __attribute__((ext_vector_type(2)));
typedef long v2i64 __attribute__((ext_vector_type(2)));

constexpr int BATCH = 2048;
constexpr int DIM   = 512;
constexpr int NCLS  = 10000;
constexpr int NPAD  = 10240;   // 80 * 128 (zero-padded rows)

#define F_S     30.0f
#define F_COS_M 0.9800665778412416f
#define F_SIN_M 0.19866933079506122f
#define F_TH   (-0.9800665778412416f)
#define F_MM    0.03973386615901224f

#define G_AAM  1280   // 16 bm x 80 bn (128x128 tiles)
#define G_CC    512   // 16 bm x 32 bn (128x64 tiles)

static __device__ __forceinline__ float clampf(float v, float lo, float hi) {
    return fminf(fmaxf(v, lo), hi);
}
// pack 4 floats -> 4 fp8 e4m3 (OCP) in one u32. Byte order is consistent across all
// matrices (same code path), so any within-pack k-permutation cancels in the dot product.
static __device__ __forceinline__ u32 pk4_fp8(float a, float b, float c, float d) {
    u32 w = __builtin_amdgcn_cvt_pk_fp8_f32(a, b, 0, false);
    w = __builtin_amdgcn_cvt_pk_fp8_f32(c, d, w, true);
    return w;
}
// async global->LDS, 16B per lane. LDS dest is wave-uniform base + lane*16.
static __device__ __forceinline__ void glds16(const void* g, void* l) {
    __builtin_amdgcn_global_load_lds(
        (const __attribute__((address_space(1))) unsigned int*)g,
        (__attribute__((address_space(3))) unsigned int*)l, 16, 0, 0);
}
static __device__ __forceinline__ float blk_sum(float v, float* sh, int t) {
#pragma unroll
    for (int o = 32; o > 0; o >>= 1) v += __shfl_down(v, o, 64);
    __syncthreads();
    if ((t & 63) == 0) sh[t >> 6] = v;
    __syncthreads();
    return sh[0] + sh[1] + sh[2] + sh[3];
}

// ============ normalize: one WAVE per row -> fp8 e4m3, ks-interleaved row layout ============
// Within each 64-elem K-block: byte offset = 16*q + 8*ks for k = ks*32 + 8q .. +8.
// One ds_read_b128 at granule q then yields [ks0 | ks1] fragments for MFMA quad q.
// Same permutation applied to ALL matrices -> dot products unaffected.
__global__ __launch_bounds__(256) void norm_all_kernel(const float* __restrict__ x,
                                                       const float* __restrict__ w,
                                                       const float* __restrict__ wm,
                                                       const float* __restrict__ wn,
                                                       const int* __restrict__ label,
                                                       u8* __restrict__ xnb,
                                                       u8* __restrict__ wb,
                                                       u8* __restrict__ wqb,
                                                       u8* __restrict__ wkb,
                                                       float* __restrict__ zacc) {
    const int t = threadIdx.x, lane = t & 63, wv = t >> 6;
    const int b = blockIdx.x;
    if (b < 33) zacc[b * 256 + t] = 0.f;   // zero accumulators (8448 >= 8196 used)

    const int row = b * 4 + wv;
    const float* src;
    u8* dst;
    const int blk = lane >> 3, ks = (lane >> 2) & 1, q = lane & 3;
    const int doff = blk * 64 + q * 16 + ks * 8;   // bijection lane -> 8B slot in 512B row

    if (row < BATCH) {
        src = x + (size_t)row * DIM;
        dst = xnb + (size_t)row * DIM;
    } else if (row < BATCH + NPAD) {
        const int r = row - BATCH;
        dst = wb + (size_t)r * DIM;
        if (r >= NCLS) {   // zero pad rows (wave-uniform)
            u32x2 z = {0, 0};
            *(u32x2*)(dst + doff) = z;
            return;
        }
        src = w + (size_t)r * DIM;
    } else if (row < BATCH + NPAD + BATCH) {
        const int i = row - (BATCH + NPAD);
        src = wm + (size_t)label[i] * DIM;
        dst = wqb + (size_t)i * DIM;
    } else {
        const int i = row - (BATCH + NPAD + BATCH);
        src = wn + (size_t)label[i] * DIM;
        dst = wkb + (size_t)i * DIM;
    }
    const float4 v0 = ((const float4*)src)[lane * 2];
    const float4 v1 = ((const float4*)src)[lane * 2 + 1];
    float s = v0.x * v0.x + v0.y * v0.y + v0.z * v0.z + v0.w * v0.w
            + v1.x * v1.x + v1.y * v1.y + v1.z * v1.z + v1.w * v1.w;
#pragma unroll
    for (int o = 32; o > 0; o >>= 1) s += __shfl_xor(s, o, 64);
    const float inv = 1.0f / fmaxf(sqrtf(s), 1e-12f);
    u32x2 o2;
    o2[0] = pk4_fp8(v0.x * inv, v0.y * inv, v0.z * inv, v0.w * inv);
    o2[1] = pk4_fp8(v1.x * inv, v1.y * inv, v1.z * inv, v1.w * inv);
    *(u32x2*)(dst + doff) = o2;
}

// ============ FUSED fp8 GEMM: [0,1280)=AAM 128x128, [1280,1792)=CC 128x64 ============
// fp8 rows = 64 B; glds staging (2 shots/tile) + XOR swizzle slot = quad^(fr&3):
// 8 lanes per 4-bank group -> balanced/conflict-free b128 reads. Staging bytes, LDS
// footprint and prologue fill all HALVE vs bf16; MFMA count unchanged (fp8 = bf16 rate).
__global__ __launch_bounds__(256) void gemm_fused_kernel(const u8* __restrict__ A,
                                                         const u8* __restrict__ Bw,
                                                         const u8* __restrict__ Bq,
                                                         const u8* __restrict__ Bk,
                                                         const int* __restrict__ label,
                                                         float* __restrict__ sumexp,
                                                         float* __restrict__ sumlogit,
                                                         float* __restrict__ philab,
                                                         float* __restrict__ sim,
                                                         float* __restrict__ msum,
                                                         float* __restrict__ mcnt,
                                                         float* __restrict__ ap) {
    __shared__ __align__(16) u8 sA[128 * 64];   // 8 KB
    __shared__ __align__(16) u8 sB[128 * 64];   // 8 KB (CC: Qs=[0,4K), Ks=[4K,8K))
    __shared__ float red0[128];
    __shared__ float red1[128];

    const int t = threadIdx.x;
    const int lane = t & 63, wave = t >> 6;
    const int fr = lane & 15, quad = lane >> 4;
    const int slot = quad ^ (fr & 3);           // wave-constant read swizzle

    if (t < 128) { red0[t] = 0.f; red1[t] = 0.f; }

    const int srow = t >> 2;                    // 0..63 (+64 on shot 1)
    const int sgr  = (t & 3) ^ (srow & 3);      // swizzled global 16B granule

    if (blockIdx.x < G_AAM) {
        // ---------------- AAM role: 128x128 tile, BK=64 ----------------
        const int flat = blockIdx.x;
        const int xcd = flat & 7, r = flat >> 3;
        const int bm = r & 15;
        const int bn = (r >> 4) * 8 + xcd;      // 10 bn per xcd -> per-XCD L2-resident

        const int wm = (wave >> 1) * 64, wn = (wave & 1) * 64;
        const u8* ag = A  + (size_t)(bm * 128 + srow) * DIM + sgr * 16;
        const u8* bg = Bw + (size_t)(bn * 128 + srow) * DIM + sgr * 16;
        u8* al = &sA[t * 16];
        u8* bl = &sB[t * 16];

        f32x4 acc[4][4] = {};

        for (int kb = 0; kb < 8; kb++) {
            const int ko = kb * 64;
            glds16(ag + ko, al);
            glds16(ag + (size_t)64 * DIM + ko, al + 4096);
            glds16(bg + ko, bl);
            glds16(bg + (size_t)64 * DIM + ko, bl + 4096);
            __syncthreads();
            v2i64 a8[4], b8[4];
#pragma unroll
            for (int f = 0; f < 4; f++) {
                a8[f] = __builtin_bit_cast(v2i64, *(const u32x4*)&sA[(wm + f * 16 + fr) * 64 + slot * 16]);
                b8[f] = __builtin_bit_cast(v2i64, *(const u32x4*)&sB[(wn + f * 16 + fr) * 64 + slot * 16]);
            }
#pragma unroll
            for (int i = 0; i < 4; i++)
#pragma unroll
                for (int j = 0; j < 4; j++) {
                    acc[i][j] = __builtin_amdgcn_mfma_f32_16x16x32_fp8_fp8(a8[i][0], b8[j][0], acc[i][j], 0, 0, 0);
                    acc[i][j] = __builtin_amdgcn_mfma_f32_16x16x32_fp8_fp8(a8[i][1], b8[j][1], acc[i][j], 0, 0, 0);
                }
            __syncthreads();
        }

        // Epilogue: per-row partial Σexp(logit), Σlogit (logits<=30 -> fp32 safe, no max-sub)
#pragma unroll
        for (int i = 0; i < 4; i++) {
#pragma unroll
            for (int r3 = 0; r3 < 4; r3++) {
                const int ml = wm + i * 16 + quad * 4 + r3;
                const int mg = bm * 128 + ml;
                const int lab = label[mg];
                float esum = 0.f, lsum = 0.f;
#pragma unroll
                for (int j = 0; j < 4; j++) {
                    const int ng = bn * 128 + wn + j * 16 + fr;
                    if (ng < NCLS) {
                        float c = acc[i][j][r3];
                        float logit;
                        if (ng == lab) {
                            float sine = sqrtf(clampf(1.f - c * c, 0.f, 1.f));
                            float phi = c * F_COS_M - sine * F_SIN_M;
                            float val = ((c - F_TH) > 0.f) ? phi : (c - F_MM);
                            logit = F_S * val;
                            philab[mg] = logit;
                        } else {
                            logit = F_S * c;
                        }
                        esum += __expf(logit);
                        lsum += logit;
                    }
                }
#pragma unroll
                for (int off = 1; off < 16; off <<= 1) {
                    esum += __shfl_xor(esum, off, 64);
                    lsum += __shfl_xor(lsum, off, 64);
                }
                if (fr == 0) {
                    atomicAdd(&red0[ml], esum);
                    atomicAdd(&red1[ml], lsum);
                }
            }
        }
        __syncthreads();
        if (t < 128) {
            atomicAdd(&sumexp[bm * 128 + t], red0[t]);
            atomicAdd(&sumlogit[bm * 128 + t], red1[t]);
        }
    } else {
        // ---------------- CC role: dual GEMM, 128x64 tile, BK=64 ----------------
        const int c = blockIdx.x - G_AAM;
        const int xcd = c & 7, r = c >> 3;
        const int bm = r & 15;
        const int bn = (r >> 4) * 8 + xcd;      // 0..31

        const int wm = (wave >> 1) * 64, wn = (wave & 1) * 32;
        u8* Qs = sB;
        u8* Ks = sB + 4096;

        const u8* ag = A  + (size_t)(bm * 128 + srow) * DIM + sgr * 16;
        const u8* qg = Bq + (size_t)(bn * 64 + srow) * DIM + sgr * 16;
        const u8* kg = Bk + (size_t)(bn * 64 + srow) * DIM + sgr * 16;
        u8* al = &sA[t * 16];
        u8* ql = &Qs[t * 16];   // 64-row tile: one 256-thread shot
        u8* kl = &Ks[t * 16];

        f32x4 aq[4][2] = {};
        f32x4 ak[4][2] = {};

        for (int kb = 0; kb < 8; kb++) {
            const int ko = kb * 64;
            glds16(ag + ko, al);
            glds16(ag + (size_t)64 * DIM + ko, al + 4096);
            glds16(qg + ko, ql);
            glds16(kg + ko, kl);
            __syncthreads();
            v2i64 a8[4], q8[2], k8[2];
#pragma unroll
            for (int f = 0; f < 4; f++)
                a8[f] = __builtin_bit_cast(v2i64, *(const u32x4*)&sA[(wm + f * 16 + fr) * 64 + slot * 16]);
#pragma unroll
            for (int f = 0; f < 2; f++) {
                q8[f] = __builtin_bit_cast(v2i64, *(const u32x4*)&Qs[(wn + f * 16 + fr) * 64 + slot * 16]);
                k8[f] = __builtin_bit_cast(v2i64, *(const u32x4*)&Ks[(wn + f * 16 + fr) * 64 + slot * 16]);
            }
#pragma unroll
            for (int i = 0; i < 4; i++)
#pragma unroll
                for (int j = 0; j < 2; j++) {
                    aq[i][j] = __builtin_amdgcn_mfma_f32_16x16x32_fp8_fp8(a8[i][0], q8[j][0], aq[i][j], 0, 0, 0);
                    aq[i][j] = __builtin_amdgcn_mfma_f32_16x16x32_fp8_fp8(a8[i][1], q8[j][1], aq[i][j], 0, 0, 0);
                    ak[i][j] = __builtin_amdgcn_mfma_f32_16x16x32_fp8_fp8(a8[i][0], k8[j][0], ak[i][j], 0, 0, 0);
                    ak[i][j] = __builtin_amdgcn_mfma_f32_16x16x32_fp8_fp8(a8[i][1], k8[j][1], ak[i][j], 0, 0, 0);
                }
            __syncthreads();
        }

        int lab_n[2];
#pragma unroll
        for (int j = 0; j < 2; j++) lab_n[j] = label[bn * 64 + wn + j * 16 + fr];

#pragma unroll
        for (int i = 0; i < 4; i++) {
#pragma unroll
            for (int r3 = 0; r3 < 4; r3++) {
                const int ml = wm + i * 16 + quad * 4 + r3;
                const int mg = bm * 128 + ml;
                const int lm = label[mg];
                float ms = 0.f, mc = 0.f;
#pragma unroll
                for (int j = 0; j < 2; j++) {
                    const int ng = bn * 64 + wn + j * 16 + fr;
                    float s = aq[i][j][r3] * ak[i][j][r3];
                    sim[(size_t)mg * BATCH + ng] = s;
                    if (lab_n[j] == lm) { ms += s; mc += 1.f; }
                    if (mg == ng) ap[mg] = s;   // unique writer; read next dispatch
                }
#pragma unroll
                for (int off = 1; off < 16; off <<= 1) {
                    ms += __shfl_xor(ms, off, 64);
                    mc += __shfl_xor(mc, off, 64);
                }
                if (fr == 0) {
                    atomicAdd(&red0[ml], ms);
                    atomicAdd(&red1[ml], mc);
                }
            }
        }
        __syncthreads();
        if (t < 128) {
            atomicAdd(&msum[bm * 128 + t], red0[t]);
            atomicAdd(&mcnt[bm * 128 + t], red1[t]);
        }
    }
}

// ============ CC pass 2 + finalize (atomics-only ticket, no fences) ============
__global__ __launch_bounds__(256) void cc_pass2_kernel(const float* __restrict__ sim,
                                                       const int* __restrict__ label,
                                                       const float* __restrict__ msum,
                                                       const float* __restrict__ mcnt,
                                                       const float* __restrict__ ap,
                                                       const float* __restrict__ sumexp,
                                                       const float* __restrict__ sumlogit,
                                                       const float* __restrict__ philab,
                                                       float* __restrict__ zn,
                                                       float* __restrict__ zneg,
                                                       float* __restrict__ accA,
                                                       unsigned* __restrict__ tick,
                                                       float* __restrict__ out) {
    __shared__ __align__(16) float cam_s[BATCH];
    __shared__ __align__(16) float sam_s[BATCH];
    __shared__ float sh[4];
    const int t = threadIdx.x, b = blockIdx.x;

    for (int j = t; j < BATCH; j += 256) {
        float cam = clampf(msum[j] / mcnt[j], 0.f, 1.f);   // mcnt >= 1 (diagonal)
        cam_s[j] = cam;
        sam_s[j] = sqrtf(clampf(1.f - cam, 0.f, 1.f));
    }
    __syncthreads();

    float acc = 0.f;
#pragma unroll
    for (int row = 0; row < 4; row++) {
        const int i = b * 4 + row;
        const int li = label[i];
        const f32x4* simr = (const f32x4*)(sim + (size_t)i * BATCH);
        const f32x4* cap4 = (const f32x4*)cam_s;
        const f32x4* sap4 = (const f32x4*)sam_s;
#pragma unroll
        for (int k = 0; k < 2; k++) {
            const int jj = t + k * 256;
            f32x4 s4 = simr[jj];
            int4 l4i = ((const int4*)label)[jj];
            const int* l4 = (const int*)&l4i;
            f32x4 ca4 = cap4[jj];
            f32x4 sa4 = sap4[jj];
#pragma unroll
            for (int e = 0; e < 4; e++) {
                if (l4[e] != li) {
                    float can = clampf(s4[e], 0.f, 1.f);
                    float san = sqrtf(clampf(1.f - can, 0.f, 1.f));
                    float pns = san * ca4[e] + can * sa4[e];   // column-j broadcast
                    float pnc = sqrtf(clampf(1.f - pns, 0.f, 1.f));
                    acc += __expf(pns * F_COS_M - pnc * F_SIN_M);
                }
            }
        }
    }
    acc = blk_sum(acc, sh, t);

    if (t == 0) {
        float apart = 0.f, epart = 0.f;
#pragma unroll
        for (int row = 0; row < 4; row++) {
            const int rr = b * 4 + row;
            float lse = logf(sumexp[rr]);
            apart += 0.9f * (philab[rr] - lse) + 1e-5f * (sumlogit[rr] - (float)NCLS * lse);
            float cam = cam_s[rr], sam = sam_s[rr];
            float cap = clampf(ap[rr], 0.f, 1.f);
            float sap = sqrtf(clampf(1.f - cap, 0.f, 1.f));
            float ppc = cap * cam - sap * sam;
            float pps = sqrtf(clampf(1.f - ppc, 0.f, 1.f));
            epart += __expf(1.f - (ppc * F_COS_M - pps * F_SIN_M));
        }
        atomicAdd(zn, acc);
        atomicAdd(accA, apart);
        atomicAdd(zneg, epart);
        unsigned old = __hip_atomic_fetch_add(tick, 1u, __ATOMIC_ACQ_REL, __HIP_MEMORY_SCOPE_AGENT);
        if (old == 511u) {   // last block: all 512 released their adds
            float znv = __hip_atomic_load(zn,   __ATOMIC_RELAXED, __HIP_MEMORY_SCOPE_AGENT);
            float aav = __hip_atomic_load(accA, __ATOMIC_RELAXED, __HIP_MEMORY_SCOPE_AGENT);
            float zgv = __hip_atomic_load(zneg, __ATOMIC_RELAXED, __HIP_MEMORY_SCOPE_AGENT);
            float aam = -aav / (float)BATCH;
            float z = logf(znv) + logf(zgv);
            float cc = (z > 0.f) ? (z + log1pf(__expf(-z))) : log1pf(__expf(z));
            out[0] = aam + cc;
        }
    }
}

extern "C" void kernel_launch(void* const* d_in, const int* in_sizes, int n_in,
                              void* d_out, int out_size, void* d_ws, size_t ws_size,
                              hipStream_t stream) {
    const float* x        = (const float*)d_in[0];
    const int*   label    = (const int*)d_in[1];
    const float* weight   = (const float*)d_in[2];
    const float* weight_m = (const float*)d_in[3];
    const float* weight_n = (const float*)d_in[4];
    float* out = (float*)d_out;
    char* ws = (char*)d_ws;

    // fp8 operand buffers (1 B/elem)
    const size_t o_xnb  = 0;                                   // 1 MB
    const size_t o_wb   = o_xnb + (size_t)BATCH * DIM;         // 5.24 MB
    const size_t o_wqb  = o_wb  + (size_t)NPAD * DIM;          // 1 MB
    const size_t o_wkb  = o_wqb + (size_t)BATCH * DIM;         // 1 MB
    const size_t o_sim  = o_wkb + (size_t)BATCH * DIM;         // 16.8 MB
    const size_t o_misc = o_sim + (size_t)BATCH * BATCH * 4;

    u8* xnb = (u8*)(ws + o_xnb);
    u8* wb  = (u8*)(ws + o_wb);
    u8* wqb = (u8*)(ws + o_wqb);
    u8* wkb = (u8*)(ws + o_wkb);
    float* sim = (float*)(ws + o_sim);
    float* mf  = (float*)(ws + o_misc);

    // zeroed by norm_all (33*256 = 8448 floats)
    float* sumexp   = mf;               // 2048
    float* sumlogit = mf + 2048;        // 2048
    float* msum     = mf + 4096;        // 2048
    float* mcnt     = mf + 6144;        // 2048
    float* zn       = mf + 8192;        // 1
    float* zneg     = mf + 8193;        // 1
    float* accA     = mf + 8194;        // 1
    unsigned* tick  = (unsigned*)(mf + 8195);
    // non-zeroed (fully overwritten every launch)
    float* philab  = mf + 8448;         // 2048
    float* ap      = mf + 10496;        // 2048

    norm_all_kernel<<<(BATCH + NPAD + 2 * BATCH) / 4, 256, 0, stream>>>(
        x, weight, weight_m, weight_n, label, xnb, wb, wqb, wkb, mf);

    gemm_fused_kernel<<<G_AAM + G_CC, 256, 0, stream>>>(
        xnb, wb, wqb, wkb, label,
        sumexp, sumlogit, philab, sim, msum, mcnt, ap);

    cc_pass2_kernel<<<512, 256, 0, stream>>>(
        sim, label, msum, mcnt, ap,
        sumexp, sumlogit, philab, zn, zneg, accA, tick, out);
}